// Round 1
// baseline (285.478 us; speedup 1.0000x reference)
//
#include <hip/hip_runtime.h>

#define NN 4096
#define HH 4

typedef __attribute__((ext_vector_type(8))) short short8;
typedef __attribute__((ext_vector_type(4))) float f32x4;

__device__ __forceinline__ unsigned short f2bf(float f) {
  union { float f; unsigned u; } v; v.f = f;
  unsigned u = v.u;
  u += 0x7fffu + ((u >> 16) & 1u);
  return (unsigned short)(u >> 16);
}

__device__ __forceinline__ unsigned pack2bf(float a, float b, float s) {
  return (unsigned)f2bf(a * s) | ((unsigned)f2bf(b * s) << 16);
}

// ---------------- projection kernel ----------------
// grid (4, 16, 3), block 256. z: 0=q,1=k,2=v.
// Emits Qb/Kb as bf16 [h][n][64] (Q pre-scaled by 1/8), Vb as bf16 [h][80][n] (rows 0..63).
__global__ __launch_bounds__(256) void proj_kernel(
    const float* __restrict__ query, const float* __restrict__ key_, const float* __restrict__ value,
    const float* __restrict__ Wq, const float* __restrict__ bq,
    const float* __restrict__ Wk, const float* __restrict__ bk,
    const float* __restrict__ Wv, const float* __restrict__ bv,
    unsigned short* __restrict__ Qb, unsigned short* __restrict__ Kb, unsigned short* __restrict__ Vb) {
  __shared__ float Wl[16][256];
  const int z = blockIdx.z;
  const float* in = (z == 0) ? query : (z == 1) ? key_ : value;
  const float* W  = (z == 0) ? Wq : (z == 1) ? Wk : Wv;
  const float* bb = (z == 0) ? bq : (z == 1) ? bk : bv;
  const int h  = blockIdx.y & 3;
  const int d0 = (blockIdx.y >> 2) << 4;
  const int tid = threadIdx.x;
  for (int idx = tid; idx < 16 * 256; idx += 256) {
    const int j = idx >> 8, ci = idx & 255;
    Wl[j][ci] = W[(((d0 + j) << 2) + h) * 256 + ci];  // row co = 4*(d0+j)+h
  }
  __syncthreads();
  const int n0 = blockIdx.x * 1024 + tid;
  float acc[16][4];
#pragma unroll
  for (int j = 0; j < 16; ++j) {
    const float bj = bb[(((d0 + j) << 2) + h)];
#pragma unroll
    for (int nn = 0; nn < 4; ++nn) acc[j][nn] = bj;
  }
  for (int c4 = 0; c4 < 256; c4 += 4) {
    float xv[4][4];
#pragma unroll
    for (int ii = 0; ii < 4; ++ii)
#pragma unroll
      for (int nn = 0; nn < 4; ++nn)
        xv[ii][nn] = in[(c4 + ii) * NN + n0 + nn * 256];
#pragma unroll
    for (int j = 0; j < 16; ++j) {
      const float4 wv = *(const float4*)&Wl[j][c4];
#pragma unroll
      for (int nn = 0; nn < 4; ++nn)
        acc[j][nn] = fmaf(wv.x, xv[0][nn],
                      fmaf(wv.y, xv[1][nn],
                      fmaf(wv.z, xv[2][nn],
                      fmaf(wv.w, xv[3][nn], acc[j][nn]))));
    }
  }
  if (z <= 1) {
    unsigned short* Ob = (z == 0) ? Qb : Kb;
    const float s = (z == 0) ? 0.125f : 1.0f;  // fold 1/sqrt(DIM) into Q
#pragma unroll
    for (int nn = 0; nn < 4; ++nn) {
      const int n = n0 + nn * 256;
      unsigned u[8];
#pragma unroll
      for (int j2 = 0; j2 < 8; ++j2)
        u[j2] = pack2bf(acc[2 * j2][nn], acc[2 * j2 + 1][nn], s);
      uint4* dst = (uint4*)(Ob + (h * NN + n) * 64 + d0);
      dst[0] = *(uint4*)&u[0];
      dst[1] = *(uint4*)&u[4];
    }
  } else {
#pragma unroll
    for (int j = 0; j < 16; ++j) {
#pragma unroll
      for (int nn = 0; nn < 4; ++nn) {
        const int n = n0 + nn * 256;
        Vb[(h * 80 + d0 + j) * NN + n] = f2bf(acc[j][nn]);
      }
    }
  }
}

// ---------------- coords fill: V rows 64..66 = coords1, 67..79 = 0 ----------------
// grid (16, 4), block 256
__global__ void coords_fill_kernel(const float* __restrict__ coords1, unsigned short* __restrict__ Vb) {
  const int n = blockIdx.x * 256 + threadIdx.x;
  const int h = blockIdx.y;
#pragma unroll
  for (int i = 0; i < 3; ++i)
    Vb[(h * 80 + 64 + i) * NN + n] = f2bf(coords1[i * NN + n]);
#pragma unroll
  for (int d = 67; d < 80; ++d)
    Vb[(h * 80 + d) * NN + n] = 0;
}

// ---------------- fused flash attention + augmentation ----------------
// grid (64, 4): x = q-tile of 64 queries, y = head. block 256 = 4 waves x 16 queries.
__global__ __launch_bounds__(256) void attn_kernel(
    const unsigned short* __restrict__ Qb, const unsigned short* __restrict__ Kb,
    const unsigned short* __restrict__ Vb, const float* __restrict__ coords0,
    float* __restrict__ y) {
  __shared__ __align__(16) unsigned char smem[26624];  // K[64][64]bf16 | Vt[80][64]bf16 | P[4][16][64]bf16
  const int h = blockIdx.y;
  const int qbase = blockIdx.x * 64;
  const int tid = threadIdx.x;
  const int w = tid >> 6;
  const int l = tid & 63;
  const int c = l & 15;   // fragment "col" lane id
  const int g = l >> 4;   // fragment k-group
  const int swc = (c & 7) << 4;

  // Q A-fragments: row = l&15 (query), elem j: d = g*8+j (+32 for frag1)
  short8 qf0, qf1;
  {
    const unsigned short* qs = Qb + (((h * NN) + qbase + w * 16 + c) << 6) + (g << 3);
    qf0 = *(const short8*)qs;
    qf1 = *(const short8*)(qs + 32);
  }
  f32x4 Of[5];
#pragma unroll
  for (int dt = 0; dt < 5; ++dt) Of[dt] = (f32x4){0.f, 0.f, 0.f, 0.f};
  float mrun[4], lrun[4];
#pragma unroll
  for (int r = 0; r < 4; ++r) { mrun[r] = -1e30f; lrun[r] = 0.f; }

  char* const Kls = (char*)smem;            // 8192 B
  char* const Vls = (char*)smem + 8192;     // 10240 B
  char* const Pls = (char*)smem + 18432 + w * 2048;  // per-wave 2048 B

  for (int m0 = 0; m0 < NN; m0 += 64) {
    __syncthreads();
    // stage K tile [key][d] and V^T tile [dv][key], XOR-swizzled 16B chunks
    {
      int idx = tid;
#pragma unroll
      for (int i = 0; i < 2; ++i, idx += 256) {
        const int row = idx >> 3, ch = idx & 7;
        const uint4 v = *(const uint4*)(Kb + ((h * NN + m0 + row) << 6) + (ch << 3));
        *(uint4*)(Kls + row * 128 + ((ch << 4) ^ ((row & 7) << 4))) = v;
      }
      idx = tid;
#pragma unroll
      for (int i = 0; i < 3; ++i, idx += 256) {
        if (idx < 640) {
          const int dv = idx >> 3, ch = idx & 7;
          const uint4 v = *(const uint4*)(Vb + (h * 80 + dv) * NN + m0 + (ch << 3));
          *(uint4*)(Vls + dv * 128 + ((ch << 4) ^ ((dv & 7) << 4))) = v;
        }
      }
    }
    __syncthreads();

    // S = Q K^T  (rows = queries, cols = keys), 4 key sub-tiles
    f32x4 sD[4];
#pragma unroll
    for (int t = 0; t < 4; ++t) {
      const char* rp = Kls + (t * 16 + c) * 128;
      const short8 b0 = *(const short8*)(rp + ((g << 4) ^ swc));
      const short8 b1 = *(const short8*)(rp + ((64 + (g << 4)) ^ swc));
      f32x4 a = (f32x4){0.f, 0.f, 0.f, 0.f};
      a = __builtin_amdgcn_mfma_f32_16x16x32_bf16(qf0, b0, a, 0, 0, 0);
      a = __builtin_amdgcn_mfma_f32_16x16x32_bf16(qf1, b1, a, 0, 0, 0);
      sD[t] = a;
    }

    // online softmax; D rows live at q=(g*4+r), reduce across the 16-lane group
    float al[4], pv[4][4];
#pragma unroll
    for (int r = 0; r < 4; ++r) {
      float mx = fmaxf(fmaxf(sD[0][r], sD[1][r]), fmaxf(sD[2][r], sD[3][r]));
      mx = fmaxf(mx, __shfl_xor(mx, 1));
      mx = fmaxf(mx, __shfl_xor(mx, 2));
      mx = fmaxf(mx, __shfl_xor(mx, 4));
      mx = fmaxf(mx, __shfl_xor(mx, 8));
      const float mnew = fmaxf(mrun[r], mx);
      al[r] = __expf(mrun[r] - mnew);
      mrun[r] = mnew;
      float rs = 0.f;
#pragma unroll
      for (int t = 0; t < 4; ++t) {
        pv[t][r] = __expf(sD[t][r] - mnew);
        rs += pv[t][r];
      }
      rs += __shfl_xor(rs, 1);
      rs += __shfl_xor(rs, 2);
      rs += __shfl_xor(rs, 4);
      rs += __shfl_xor(rs, 8);
      lrun[r] = lrun[r] * al[r] + rs;
    }
#pragma unroll
    for (int dt = 0; dt < 5; ++dt)
#pragma unroll
      for (int r = 0; r < 4; ++r) Of[dt][r] *= al[r];

    // P -> bf16 -> per-wave LDS (swizzled), reload as A-fragments
#pragma unroll
    for (int t = 0; t < 4; ++t)
#pragma unroll
      for (int r = 0; r < 4; ++r) {
        const int q = (g << 2) + r;
        *(unsigned short*)(Pls + q * 128 + (((t * 16 + c) * 2) ^ ((q & 7) << 4))) = f2bf(pv[t][r]);
      }
    {
      const char* pp = Pls + c * 128;
      const short8 pa0 = *(const short8*)(pp + ((g << 4) ^ swc));
      const short8 pa1 = *(const short8*)(pp + ((64 + (g << 4)) ^ swc));
#pragma unroll
      for (int dt = 0; dt < 5; ++dt) {
        const int dv = dt * 16 + c;
        const char* vp = Vls + dv * 128;
        const int sv = (dv & 7) << 4;
        const short8 vb0 = *(const short8*)(vp + ((g << 4) ^ sv));
        const short8 vb1 = *(const short8*)(vp + ((64 + (g << 4)) ^ sv));
        Of[dt] = __builtin_amdgcn_mfma_f32_16x16x32_bf16(pa0, vb0, Of[dt], 0, 0, 0);
        Of[dt] = __builtin_amdgcn_mfma_f32_16x16x32_bf16(pa1, vb1, Of[dt], 0, 0, 0);
      }
    }
  }

  // epilogue: normalize, transpose via LDS, fuse aug1/aug2, write y[dy*4+h][n]
  float inv[4];
#pragma unroll
  for (int r = 0; r < 4; ++r) inv[r] = 1.0f / lrun[r];
  __syncthreads();
  float* Old = (float*)smem;  // [64][stride 83]
#pragma unroll
  for (int dt = 0; dt < 5; ++dt)
#pragma unroll
    for (int r = 0; r < 4; ++r)
      Old[(w * 16 + (g << 2) + r) * 83 + dt * 16 + c] = Of[dt][r] * inv[r];
  __syncthreads();
  {
    const int q = tid & 63;
    const int part = tid >> 6;
    const int qg = qbase + q;
    const int dy0 = part * 18;
    const int dy1 = (dy0 + 18 < 71) ? dy0 + 18 : 71;
    for (int dy = dy0; dy < dy1; ++dy) {
      float val;
      if (dy < 67) {
        val = Old[q * 83 + dy];
      } else if (dy < 70) {
        val = Old[q * 83 + 64 + (dy - 67)] - coords0[(dy - 67) * NN + qg];
      } else {
        float ssum = 0.f;
#pragma unroll
        for (int i = 0; i < 3; ++i) {
          const float a = Old[q * 83 + 64 + i] - coords0[i * NN + qg];
          ssum += a * a;
        }
        val = sqrtf(ssum);
      }
      y[(dy * 4 + h) * NN + qg] = val;
    }
  }
}

// ---------------- final 284x284 projection ----------------
// grid (4, 36), block 256
__global__ __launch_bounds__(256) void outproj_kernel(
    const float* __restrict__ y, const float* __restrict__ Wm, const float* __restrict__ bm,
    float* __restrict__ out) {
  __shared__ float Wl[8][284];
  const int co0 = blockIdx.y * 8;
  const int tid = threadIdx.x;
  for (int idx = tid; idx < 8 * 284; idx += 256) {
    const int j = idx / 284, ci = idx - j * 284;
    const int co = co0 + j;
    Wl[j][ci] = (co < 284) ? Wm[co * 284 + ci] : 0.f;
  }
  __syncthreads();
  const int n0 = blockIdx.x * 1024 + tid;
  float acc[8][4];
#pragma unroll
  for (int j = 0; j < 8; ++j) {
    const int co = co0 + j;
    const float bj = (co < 284) ? bm[co] : 0.f;
#pragma unroll
    for (int nn = 0; nn < 4; ++nn) acc[j][nn] = bj;
  }
  for (int c4 = 0; c4 < 284; c4 += 4) {
    float xv[4][4];
#pragma unroll
    for (int ii = 0; ii < 4; ++ii)
#pragma unroll
      for (int nn = 0; nn < 4; ++nn)
        xv[ii][nn] = y[(c4 + ii) * NN + n0 + nn * 256];
#pragma unroll
    for (int j = 0; j < 8; ++j) {
      const float4 wv = *(const float4*)&Wl[j][c4];
#pragma unroll
      for (int nn = 0; nn < 4; ++nn)
        acc[j][nn] = fmaf(wv.x, xv[0][nn],
                      fmaf(wv.y, xv[1][nn],
                      fmaf(wv.z, xv[2][nn],
                      fmaf(wv.w, xv[3][nn], acc[j][nn]))));
    }
  }
#pragma unroll
  for (int j = 0; j < 8; ++j) {
    const int co = co0 + j;
    if (co < 284) {
#pragma unroll
      for (int nn = 0; nn < 4; ++nn)
        out[co * NN + n0 + nn * 256] = acc[j][nn];
    }
  }
}

extern "C" void kernel_launch(void* const* d_in, const int* in_sizes, int n_in,
                              void* d_out, int out_size, void* d_ws, size_t ws_size,
                              hipStream_t stream) {
  const float* query   = (const float*)d_in[0];
  const float* key_    = (const float*)d_in[1];
  const float* value   = (const float*)d_in[2];
  const float* coords0 = (const float*)d_in[3];
  const float* coords1 = (const float*)d_in[4];
  const float* Wq = (const float*)d_in[5];
  const float* bq = (const float*)d_in[6];
  const float* Wk = (const float*)d_in[7];
  const float* bk = (const float*)d_in[8];
  const float* Wv = (const float*)d_in[9];
  const float* bv = (const float*)d_in[10];
  const float* Wm = (const float*)d_in[11];
  const float* bm = (const float*)d_in[12];
  float* out = (float*)d_out;

  // workspace layout (bytes): Qb 2MB | Kb 2MB | Vb 2.62MB | y 4.65MB  (~11.3 MB total)
  unsigned short* Qb = (unsigned short*)d_ws;
  unsigned short* Kb = Qb + 4 * NN * 64;
  unsigned short* Vb = Kb + 4 * NN * 64;
  float* y = (float*)(Vb + 4 * 80 * NN);

  hipLaunchKernelGGL(proj_kernel, dim3(4, 16, 3), dim3(256), 0, stream,
                     query, key_, value, Wq, bq, Wk, bk, Wv, bv, Qb, Kb, Vb);
  hipLaunchKernelGGL(coords_fill_kernel, dim3(16, 4), dim3(256), 0, stream, coords1, Vb);
  hipLaunchKernelGGL(attn_kernel, dim3(64, 4), dim3(256), 0, stream, Qb, Kb, Vb, coords0, y);
  hipLaunchKernelGGL(outproj_kernel, dim3(4, 36), dim3(256), 0, stream, y, Wm, bm, out);
}

// Round 2
// 199.534 us; speedup vs baseline: 1.4307x; 1.4307x over previous
//
#include <hip/hip_runtime.h>

#define NN 4096
#define HH 4

typedef __attribute__((ext_vector_type(8))) short short8;
typedef __attribute__((ext_vector_type(4))) float f32x4;

__device__ __forceinline__ unsigned short f2bf(float f) {
  union { float f; unsigned u; } v; v.f = f;
  unsigned u = v.u;
  u += 0x7fffu + ((u >> 16) & 1u);
  return (unsigned short)(u >> 16);
}

__device__ __forceinline__ unsigned pack2bf(float a, float b, float s) {
  return (unsigned)f2bf(a * s) | ((unsigned)f2bf(b * s) << 16);
}

// ---------------- projection kernel ----------------
// grid (16, 16, 3), block 256. z: 0=q,1=k,2=v. Per-thread: 16 out-ch x 1 n.
// Emits Qb/Kb as bf16 [h][n][64] (Q pre-scaled by 1/8), Vb as bf16 [h][80][n] (rows 0..63).
__global__ __launch_bounds__(256) void proj_kernel(
    const float* __restrict__ query, const float* __restrict__ key_, const float* __restrict__ value,
    const float* __restrict__ Wq, const float* __restrict__ bq,
    const float* __restrict__ Wk, const float* __restrict__ bk,
    const float* __restrict__ Wv, const float* __restrict__ bv,
    unsigned short* __restrict__ Qb, unsigned short* __restrict__ Kb, unsigned short* __restrict__ Vb) {
  __shared__ float Wl[16][256];
  const int z = blockIdx.z;
  const float* in = (z == 0) ? query : (z == 1) ? key_ : value;
  const float* W  = (z == 0) ? Wq : (z == 1) ? Wk : Wv;
  const float* bb = (z == 0) ? bq : (z == 1) ? bk : bv;
  const int h  = blockIdx.y & 3;
  const int d0 = (blockIdx.y >> 2) << 4;
  const int tid = threadIdx.x;
  for (int idx = tid; idx < 16 * 256; idx += 256) {
    const int j = idx >> 8, ci = idx & 255;
    Wl[j][ci] = W[(((d0 + j) << 2) + h) * 256 + ci];  // row co = 4*(d0+j)+h
  }
  __syncthreads();
  const int n = blockIdx.x * 256 + tid;
  float acc[16];
#pragma unroll
  for (int j = 0; j < 16; ++j) acc[j] = bb[(((d0 + j) << 2) + h)];
  for (int c4 = 0; c4 < 256; c4 += 4) {
    const float x0 = in[(c4 + 0) * NN + n];
    const float x1 = in[(c4 + 1) * NN + n];
    const float x2 = in[(c4 + 2) * NN + n];
    const float x3 = in[(c4 + 3) * NN + n];
#pragma unroll
    for (int j = 0; j < 16; ++j) {
      const float4 wv = *(const float4*)&Wl[j][c4];
      acc[j] = fmaf(wv.x, x0, fmaf(wv.y, x1, fmaf(wv.z, x2, fmaf(wv.w, x3, acc[j]))));
    }
  }
  if (z <= 1) {
    unsigned short* Ob = (z == 0) ? Qb : Kb;
    const float s = (z == 0) ? 0.125f : 1.0f;  // fold 1/sqrt(DIM) into Q
    unsigned u[8];
#pragma unroll
    for (int j2 = 0; j2 < 8; ++j2)
      u[j2] = pack2bf(acc[2 * j2], acc[2 * j2 + 1], s);
    uint4* dst = (uint4*)(Ob + (h * NN + n) * 64 + d0);
    dst[0] = *(uint4*)&u[0];
    dst[1] = *(uint4*)&u[4];
  } else {
#pragma unroll
    for (int j = 0; j < 16; ++j)
      Vb[(h * 80 + d0 + j) * NN + n] = f2bf(acc[j]);
  }
}

// ---------------- coords fill: V rows 64..66 = coords1, 67..79 = 0 ----------------
// grid (16, 4), block 256
__global__ void coords_fill_kernel(const float* __restrict__ coords1, unsigned short* __restrict__ Vb) {
  const int n = blockIdx.x * 256 + threadIdx.x;
  const int h = blockIdx.y;
#pragma unroll
  for (int i = 0; i < 3; ++i)
    Vb[(h * 80 + 64 + i) * NN + n] = f2bf(coords1[i * NN + n]);
#pragma unroll
  for (int d = 67; d < 80; ++d)
    Vb[(h * 80 + d) * NN + n] = 0;
}

// ---------------- fused flash attention (split-K partials) ----------------
// grid (64, 4, nsplit): x = q-tile of 64, y = head, z = key-split.
// block 256 = 4 waves x 16 queries. Writes unnormalized O + (m,l) to Opart.
// Opart layout: [(split*4+h)*69 + dv][q], dv 0..66 = O, 67 = m, 68 = l.
__global__ __launch_bounds__(256) void attn_kernel(
    const unsigned short* __restrict__ Qb, const unsigned short* __restrict__ Kb,
    const unsigned short* __restrict__ Vb, float* __restrict__ Opart, int chunkKeys) {
  __shared__ __align__(16) unsigned char smem[26624];  // K[64][64]bf16 | Vt[80][64]bf16 | P[4][16][64]bf16
  const int h = blockIdx.y;
  const int sp = blockIdx.z;
  const int qbase = blockIdx.x * 64;
  const int tid = threadIdx.x;
  const int w = tid >> 6;
  const int l = tid & 63;
  const int c = l & 15;   // fragment "col" lane id
  const int g = l >> 4;   // fragment k-group
  const int swc = (c & 7) << 4;

  short8 qf0, qf1;
  {
    const unsigned short* qs = Qb + (((h * NN) + qbase + w * 16 + c) << 6) + (g << 3);
    qf0 = *(const short8*)qs;
    qf1 = *(const short8*)(qs + 32);
  }
  f32x4 Of[5];
#pragma unroll
  for (int dt = 0; dt < 5; ++dt) Of[dt] = (f32x4){0.f, 0.f, 0.f, 0.f};
  float mrun[4], lrun[4];
#pragma unroll
  for (int r = 0; r < 4; ++r) { mrun[r] = -1e30f; lrun[r] = 0.f; }

  char* const Kls = (char*)smem;            // 8192 B
  char* const Vls = (char*)smem + 8192;     // 10240 B
  char* const Pls = (char*)smem + 18432 + w * 2048;  // per-wave 2048 B

  const int mEnd = (sp + 1) * chunkKeys;
  for (int m0 = sp * chunkKeys; m0 < mEnd; m0 += 64) {
    __syncthreads();
    {
      int idx = tid;
#pragma unroll
      for (int i = 0; i < 2; ++i, idx += 256) {
        const int row = idx >> 3, ch = idx & 7;
        const uint4 v = *(const uint4*)(Kb + ((h * NN + m0 + row) << 6) + (ch << 3));
        *(uint4*)(Kls + row * 128 + ((ch << 4) ^ ((row & 7) << 4))) = v;
      }
      idx = tid;
#pragma unroll
      for (int i = 0; i < 3; ++i, idx += 256) {
        if (idx < 640) {
          const int dv = idx >> 3, ch = idx & 7;
          const uint4 v = *(const uint4*)(Vb + (h * 80 + dv) * NN + m0 + (ch << 3));
          *(uint4*)(Vls + dv * 128 + ((ch << 4) ^ ((dv & 7) << 4))) = v;
        }
      }
    }
    __syncthreads();

    // S = Q K^T
    f32x4 sD[4];
    __builtin_amdgcn_s_setprio(1);
#pragma unroll
    for (int t = 0; t < 4; ++t) {
      const char* rp = Kls + (t * 16 + c) * 128;
      const short8 b0 = *(const short8*)(rp + ((g << 4) ^ swc));
      const short8 b1 = *(const short8*)(rp + ((64 + (g << 4)) ^ swc));
      f32x4 a = (f32x4){0.f, 0.f, 0.f, 0.f};
      a = __builtin_amdgcn_mfma_f32_16x16x32_bf16(qf0, b0, a, 0, 0, 0);
      a = __builtin_amdgcn_mfma_f32_16x16x32_bf16(qf1, b1, a, 0, 0, 0);
      sD[t] = a;
    }
    __builtin_amdgcn_s_setprio(0);

    // online softmax; D rows live at q=(g*4+r), reduce across the 16-lane group
    float al[4], pv[4][4];
#pragma unroll
    for (int r = 0; r < 4; ++r) {
      float mx = fmaxf(fmaxf(sD[0][r], sD[1][r]), fmaxf(sD[2][r], sD[3][r]));
      mx = fmaxf(mx, __shfl_xor(mx, 1));
      mx = fmaxf(mx, __shfl_xor(mx, 2));
      mx = fmaxf(mx, __shfl_xor(mx, 4));
      mx = fmaxf(mx, __shfl_xor(mx, 8));
      const float mnew = fmaxf(mrun[r], mx);
      al[r] = __expf(mrun[r] - mnew);
      mrun[r] = mnew;
      float rs = 0.f;
#pragma unroll
      for (int t = 0; t < 4; ++t) {
        pv[t][r] = __expf(sD[t][r] - mnew);
        rs += pv[t][r];
      }
      rs += __shfl_xor(rs, 1);
      rs += __shfl_xor(rs, 2);
      rs += __shfl_xor(rs, 4);
      rs += __shfl_xor(rs, 8);
      lrun[r] = lrun[r] * al[r] + rs;
    }
#pragma unroll
    for (int dt = 0; dt < 5; ++dt)
#pragma unroll
      for (int r = 0; r < 4; ++r) Of[dt][r] *= al[r];

    // P -> bf16 -> per-wave LDS (swizzled), reload as A-fragments
#pragma unroll
    for (int t = 0; t < 4; ++t)
#pragma unroll
      for (int r = 0; r < 4; ++r) {
        const int q = (g << 2) + r;
        *(unsigned short*)(Pls + q * 128 + (((t * 16 + c) * 2) ^ ((q & 7) << 4))) = f2bf(pv[t][r]);
      }
    {
      const char* pp = Pls + c * 128;
      const short8 pa0 = *(const short8*)(pp + ((g << 4) ^ swc));
      const short8 pa1 = *(const short8*)(pp + ((64 + (g << 4)) ^ swc));
      __builtin_amdgcn_s_setprio(1);
#pragma unroll
      for (int dt = 0; dt < 5; ++dt) {
        const int dv = dt * 16 + c;
        const char* vp = Vls + dv * 128;
        const int sv = (dv & 7) << 4;
        const short8 vb0 = *(const short8*)(vp + ((g << 4) ^ sv));
        const short8 vb1 = *(const short8*)(vp + ((64 + (g << 4)) ^ sv));
        Of[dt] = __builtin_amdgcn_mfma_f32_16x16x32_bf16(pa0, vb0, Of[dt], 0, 0, 0);
        Of[dt] = __builtin_amdgcn_mfma_f32_16x16x32_bf16(pa1, vb1, Of[dt], 0, 0, 0);
      }
      __builtin_amdgcn_s_setprio(0);
    }
  }

  // epilogue: transpose via LDS, write unnormalized partials + m,l (coalesced)
  __syncthreads();
  float* Old = (float*)smem;  // [64][stride 83]; cols 0..79 = O, 80 = m, 81 = l
#pragma unroll
  for (int dt = 0; dt < 5; ++dt)
#pragma unroll
    for (int r = 0; r < 4; ++r)
      Old[(w * 16 + (g << 2) + r) * 83 + dt * 16 + c] = Of[dt][r];
  if (c == 0) {
#pragma unroll
    for (int r = 0; r < 4; ++r) {
      Old[(w * 16 + (g << 2) + r) * 83 + 80] = mrun[r];
      Old[(w * 16 + (g << 2) + r) * 83 + 81] = lrun[r];
    }
  }
  __syncthreads();
  {
    const int q = tid & 63;
    const int part = tid >> 6;
    const int qg = qbase + q;
    const int rowbase = (sp * 4 + h) * 69;
    const int dy0 = part * 18;
    const int dy1 = (dy0 + 18 < 69) ? dy0 + 18 : 69;
    for (int dy = dy0; dy < dy1; ++dy) {
      float val;
      if (dy < 67)       val = Old[q * 83 + dy];
      else if (dy == 67) val = Old[q * 83 + 80];
      else               val = Old[q * 83 + 81];
      Opart[(rowbase + dy) * NN + qg] = val;
    }
  }
}

// ---------------- combine: merge splits, augment, write y ----------------
// grid (16, 4, 4): x = q-chunk of 256, y = head, z = dv-chunk
__global__ __launch_bounds__(256) void combine_kernel(
    const float* __restrict__ Opart, const float* __restrict__ coords0,
    float* __restrict__ y, int nsplit) {
  const int q = blockIdx.x * 256 + threadIdx.x;
  const int h = blockIdx.y;
  const int z = blockIdx.z;
  float m[4], w[4];
  float M = -1e30f;
  for (int s = 0; s < nsplit; ++s) {
    m[s] = Opart[((s * 4 + h) * 69 + 67) * NN + q];
    M = fmaxf(M, m[s]);
  }
  float L = 0.f;
  for (int s = 0; s < nsplit; ++s) {
    w[s] = __expf(m[s] - M);
    L += Opart[((s * 4 + h) * 69 + 68) * NN + q] * w[s];
  }
  const float invL = 1.f / L;
  if (z < 3) {
    const int dv0 = z * 17, dv1 = dv0 + 17;
    for (int dv = dv0; dv < dv1; ++dv) {
      float a = 0.f;
      for (int s = 0; s < nsplit; ++s)
        a += Opart[((s * 4 + h) * 69 + dv) * NN + q] * w[s];
      y[(dv * 4 + h) * NN + q] = a * invL;
    }
  } else {
    float ssum = 0.f;
    for (int dv = 51; dv < 67; ++dv) {
      float a = 0.f;
      for (int s = 0; s < nsplit; ++s)
        a += Opart[((s * 4 + h) * 69 + dv) * NN + q] * w[s];
      a *= invL;
      y[(dv * 4 + h) * NN + q] = a;
      if (dv >= 64) {
        const float aug = a - coords0[(dv - 64) * NN + q];
        y[((dv + 3) * 4 + h) * NN + q] = aug;
        ssum += aug * aug;
      }
    }
    y[(70 * 4 + h) * NN + q] = sqrtf(ssum);
  }
}

// ---------------- final 284x284 projection ----------------
// grid (16, 36), block 256. Per-thread: 8 out-ch x 1 n.
__global__ __launch_bounds__(256) void outproj_kernel(
    const float* __restrict__ y, const float* __restrict__ Wm, const float* __restrict__ bm,
    float* __restrict__ out) {
  __shared__ float Wl[8][284];
  const int co0 = blockIdx.y * 8;
  const int tid = threadIdx.x;
  for (int idx = tid; idx < 8 * 284; idx += 256) {
    const int j = idx / 284, ci = idx - j * 284;
    const int co = co0 + j;
    Wl[j][ci] = (co < 284) ? Wm[co * 284 + ci] : 0.f;
  }
  __syncthreads();
  const int n = blockIdx.x * 256 + tid;
  float acc[8];
#pragma unroll
  for (int j = 0; j < 8; ++j) {
    const int co = co0 + j;
    acc[j] = (co < 284) ? bm[co] : 0.f;
  }
  for (int c4 = 0; c4 < 284; c4 += 4) {
    const float x0 = y[(c4 + 0) * NN + n];
    const float x1 = y[(c4 + 1) * NN + n];
    const float x2 = y[(c4 + 2) * NN + n];
    const float x3 = y[(c4 + 3) * NN + n];
#pragma unroll
    for (int j = 0; j < 8; ++j) {
      const float4 wv = *(const float4*)&Wl[j][c4];
      acc[j] = fmaf(wv.x, x0, fmaf(wv.y, x1, fmaf(wv.z, x2, fmaf(wv.w, x3, acc[j]))));
    }
  }
#pragma unroll
  for (int j = 0; j < 8; ++j) {
    const int co = co0 + j;
    if (co < 284) out[co * NN + n] = acc[j];
  }
}

extern "C" void kernel_launch(void* const* d_in, const int* in_sizes, int n_in,
                              void* d_out, int out_size, void* d_ws, size_t ws_size,
                              hipStream_t stream) {
  const float* query   = (const float*)d_in[0];
  const float* key_    = (const float*)d_in[1];
  const float* value   = (const float*)d_in[2];
  const float* coords0 = (const float*)d_in[3];
  const float* coords1 = (const float*)d_in[4];
  const float* Wq = (const float*)d_in[5];
  const float* bq = (const float*)d_in[6];
  const float* Wk = (const float*)d_in[7];
  const float* bk = (const float*)d_in[8];
  const float* Wv = (const float*)d_in[9];
  const float* bv = (const float*)d_in[10];
  const float* Wm = (const float*)d_in[11];
  const float* bm = (const float*)d_in[12];
  float* out = (float*)d_out;

  // ws layout: Qb 2MB | Kb 2MB | Vb 2.62MB | y 4.65MB | Opart nsplit*4.52MB
  const size_t base = (size_t)4 * NN * 64 * 2 * 2 + (size_t)4 * 80 * NN * 2 + (size_t)284 * NN * 4;
  const size_t per  = (size_t)4 * 69 * NN * 4;
  int nsplit = 4;
  if (ws_size < base + 4 * per) nsplit = (ws_size >= base + 2 * per) ? 2 : 1;

  unsigned short* Qb = (unsigned short*)d_ws;
  unsigned short* Kb = Qb + 4 * NN * 64;
  unsigned short* Vb = Kb + 4 * NN * 64;
  float* y = (float*)(Vb + 4 * 80 * NN);
  float* Opart = y + (size_t)284 * NN;

  hipLaunchKernelGGL(proj_kernel, dim3(16, 16, 3), dim3(256), 0, stream,
                     query, key_, value, Wq, bq, Wk, bk, Wv, bv, Qb, Kb, Vb);
  hipLaunchKernelGGL(coords_fill_kernel, dim3(16, 4), dim3(256), 0, stream, coords1, Vb);
  hipLaunchKernelGGL(attn_kernel, dim3(64, 4, nsplit), dim3(256), 0, stream,
                     Qb, Kb, Vb, Opart, NN / nsplit);
  hipLaunchKernelGGL(combine_kernel, dim3(16, 4, 4), dim3(256), 0, stream,
                     Opart, coords0, y, nsplit);
  hipLaunchKernelGGL(outproj_kernel, dim3(16, 36), dim3(256), 0, stream, y, Wm, bm, out);
}

// Round 3
// 176.570 us; speedup vs baseline: 1.6168x; 1.1301x over previous
//
#include <hip/hip_runtime.h>
#include <hip/hip_bf16.h>

#define NN 4096

typedef __attribute__((ext_vector_type(8))) short short8;
typedef __attribute__((ext_vector_type(4))) float f32x4;

__device__ __forceinline__ unsigned short f2bf(float f) {
  union { float f; unsigned u; } v; v.f = f;
  unsigned u = v.u;
  u += 0x7fffu + ((u >> 16) & 1u);
  return (unsigned short)(u >> 16);
}

__device__ __forceinline__ unsigned pack2bf(float a, float b, float s) {
  return (unsigned)f2bf(a * s) | ((unsigned)f2bf(b * s) << 16);
}

__device__ __forceinline__ unsigned packpair(float a, float b) {
  __hip_bfloat162 h = __float22bfloat162_rn(make_float2(a, b));  // v_cvt_pk_bf16_f32
  union { __hip_bfloat162 h; unsigned u; } cv; cv.h = h;
  return cv.u;
}

// ---------------- projection kernel ----------------
// grid (16, 16, 3), block 256. z: 0=q,1=k,2=v. Per-thread: 16 out-ch x 1 n.
// Emits Qb/Kb as bf16 [h][n][64] (Q pre-scaled by 1/8), Vb as bf16 [h][80][n] (rows 0..63).
__global__ __launch_bounds__(256) void proj_kernel(
    const float* __restrict__ query, const float* __restrict__ key_, const float* __restrict__ value,
    const float* __restrict__ Wq, const float* __restrict__ bq,
    const float* __restrict__ Wk, const float* __restrict__ bk,
    const float* __restrict__ Wv, const float* __restrict__ bv,
    unsigned short* __restrict__ Qb, unsigned short* __restrict__ Kb, unsigned short* __restrict__ Vb) {
  __shared__ float Wl[16][256];
  const int z = blockIdx.z;
  const float* in = (z == 0) ? query : (z == 1) ? key_ : value;
  const float* W  = (z == 0) ? Wq : (z == 1) ? Wk : Wv;
  const float* bb = (z == 0) ? bq : (z == 1) ? bk : bv;
  const int h  = blockIdx.y & 3;
  const int d0 = (blockIdx.y >> 2) << 4;
  const int tid = threadIdx.x;
  for (int idx = tid; idx < 16 * 256; idx += 256) {
    const int j = idx >> 8, ci = idx & 255;
    Wl[j][ci] = W[(((d0 + j) << 2) + h) * 256 + ci];
  }
  __syncthreads();
  const int n = blockIdx.x * 256 + tid;
  float acc[16];
#pragma unroll
  for (int j = 0; j < 16; ++j) acc[j] = bb[(((d0 + j) << 2) + h)];
  for (int c4 = 0; c4 < 256; c4 += 4) {
    const float x0 = in[(c4 + 0) * NN + n];
    const float x1 = in[(c4 + 1) * NN + n];
    const float x2 = in[(c4 + 2) * NN + n];
    const float x3 = in[(c4 + 3) * NN + n];
#pragma unroll
    for (int j = 0; j < 16; ++j) {
      const float4 wv = *(const float4*)&Wl[j][c4];
      acc[j] = fmaf(wv.x, x0, fmaf(wv.y, x1, fmaf(wv.z, x2, fmaf(wv.w, x3, acc[j]))));
    }
  }
  if (z <= 1) {
    unsigned short* Ob = (z == 0) ? Qb : Kb;
    const float s = (z == 0) ? 0.125f : 1.0f;
    unsigned u[8];
#pragma unroll
    for (int j2 = 0; j2 < 8; ++j2)
      u[j2] = pack2bf(acc[2 * j2], acc[2 * j2 + 1], s);
    uint4* dst = (uint4*)(Ob + (h * NN + n) * 64 + d0);
    dst[0] = *(uint4*)&u[0];
    dst[1] = *(uint4*)&u[4];
  } else {
#pragma unroll
    for (int j = 0; j < 16; ++j)
      Vb[(h * 80 + d0 + j) * NN + n] = f2bf(acc[j]);
  }
}

// ---------------- coords fill: V rows 64..66 = coords1, 67..79 = 0 ----------------
__global__ void coords_fill_kernel(const float* __restrict__ coords1, unsigned short* __restrict__ Vb) {
  const int n = blockIdx.x * 256 + threadIdx.x;
  const int h = blockIdx.y;
#pragma unroll
  for (int i = 0; i < 3; ++i)
    Vb[(h * 80 + 64 + i) * NN + n] = f2bf(coords1[i * NN + n]);
#pragma unroll
  for (int d = 67; d < 80; ++d)
    Vb[(h * 80 + d) * NN + n] = 0;
}

// ---------------- fused flash attention (split-K, swapped-S^T, async stage) ----------------
// grid (32, 4, nsplit): x = q-tile of 128, y = head, z = key-split.
// block 256 = 4 waves; wave covers 32 queries (2 subtiles of 16).
// Opart layout: [(split*4+h)*69 + dv][q], dv 0..66 = unnormalized O, 67 = m, 68 = l.
__global__ __launch_bounds__(256) void attn_kernel(
    const unsigned short* __restrict__ Qb, const unsigned short* __restrict__ Kb,
    const unsigned short* __restrict__ Vb, float* __restrict__ Opart, int chunkKeys) {
  __shared__ __align__(16) unsigned char smem[34816];  // K 8192 | Vt 10240 | P 4x4096
  const int h = blockIdx.y;
  const int sp = blockIdx.z;
  const int qbase = blockIdx.x * 128;
  const int tid = threadIdx.x;
  const int w = tid >> 6;
  const int l = tid & 63;
  const int c = l & 15;   // query-in-subtile (D col) / LDS row selector
  const int g = l >> 4;   // k-group
  const int swc = (c & 7) << 4;

  char* const Kls = (char*)smem;
  char* const Vls = (char*)smem + 8192;
  char* const Pls = (char*)smem + 18432 + w * 4096;

  // Q fragments (used as MFMA B operand): col=c -> query, elems d = g*8+j (+32)
  short8 qf[2][2];
#pragma unroll
  for (int qs = 0; qs < 2; ++qs) {
    const unsigned short* qsrc = Qb + (((h * NN) + qbase + w * 32 + qs * 16 + c) << 6) + (g << 3);
    qf[qs][0] = *(const short8*)qsrc;
    qf[qs][1] = *(const short8*)(qsrc + 32);
  }

  f32x4 Of[2][5];
#pragma unroll
  for (int qs = 0; qs < 2; ++qs)
#pragma unroll
    for (int dt = 0; dt < 5; ++dt) Of[qs][dt] = (f32x4){0.f, 0.f, 0.f, 0.f};
  float mrun[2] = {-1e30f, -1e30f};
  float lrun[2] = {0.f, 0.f};

  const int r0 = tid >> 3, ch = tid & 7;
  const int so = (ch << 4) ^ ((r0 & 7) << 4);  // (r0+32)&7 == r0&7, (r0+64)&7 == r0&7
  const int mStart = sp * chunkKeys;
  const int niter = chunkKeys >> 6;

  // ---- prologue: stage tile 0 ----
  {
    const unsigned short* kbase = Kb + ((h * NN + mStart) << 6);
    const unsigned short* vbase = Vb + (size_t)(h * 80) * NN + mStart;
    const uint4 ka  = *(const uint4*)(kbase + (r0 << 6) + (ch << 3));
    const uint4 kb2 = *(const uint4*)(kbase + ((r0 + 32) << 6) + (ch << 3));
    const uint4 va  = *(const uint4*)(vbase + (size_t)r0 * NN + (ch << 3));
    const uint4 vb2 = *(const uint4*)(vbase + (size_t)(r0 + 32) * NN + (ch << 3));
    *(uint4*)(Kls + r0 * 128 + so) = ka;
    *(uint4*)(Kls + (r0 + 32) * 128 + so) = kb2;
    *(uint4*)(Vls + r0 * 128 + so) = va;
    *(uint4*)(Vls + (r0 + 32) * 128 + so) = vb2;
    if (tid < 128) {
      const uint4 vc = *(const uint4*)(vbase + (size_t)(r0 + 64) * NN + (ch << 3));
      *(uint4*)(Vls + (r0 + 64) * 128 + so) = vc;
    }
  }
  __syncthreads();

  for (int it = 0; it < niter; ++it) {
    // ---- issue next tile's loads (latency hides under compute) ----
    uint4 ka, kb2, va, vb2, vc;
    const bool hav = (it + 1 < niter);
    if (hav) {
      const int m0 = mStart + ((it + 1) << 6);
      const unsigned short* kbase = Kb + ((h * NN + m0) << 6);
      const unsigned short* vbase = Vb + (size_t)(h * 80) * NN + m0;
      ka  = *(const uint4*)(kbase + (r0 << 6) + (ch << 3));
      kb2 = *(const uint4*)(kbase + ((r0 + 32) << 6) + (ch << 3));
      va  = *(const uint4*)(vbase + (size_t)r0 * NN + (ch << 3));
      vb2 = *(const uint4*)(vbase + (size_t)(r0 + 32) * NN + (ch << 3));
      if (tid < 128) vc = *(const uint4*)(vbase + (size_t)(r0 + 64) * NN + (ch << 3));
    }

    // ---- S^T = K·Q^T : D[key=t*16+g*4+r][query=c] ----
    f32x4 sD[2][4];
    __builtin_amdgcn_s_setprio(1);
#pragma unroll
    for (int t = 0; t < 4; ++t) {
      const char* rp = Kls + (t * 16 + c) * 128;
      const short8 ka0 = *(const short8*)(rp + ((g << 4) ^ swc));
      const short8 ka1 = *(const short8*)(rp + ((64 + (g << 4)) ^ swc));
#pragma unroll
      for (int qs = 0; qs < 2; ++qs) {
        f32x4 a = (f32x4){0.f, 0.f, 0.f, 0.f};
        a = __builtin_amdgcn_mfma_f32_16x16x32_bf16(ka0, qf[qs][0], a, 0, 0, 0);
        a = __builtin_amdgcn_mfma_f32_16x16x32_bf16(ka1, qf[qs][1], a, 0, 0, 0);
        sD[qs][t] = a;
      }
    }
    __builtin_amdgcn_s_setprio(0);

    // ---- online softmax: per-lane scalar m/l (16 local keys + 2 shfl) ----
    float al[2];
#pragma unroll
    for (int qs = 0; qs < 2; ++qs) {
      float m01 = fmaxf(fmaxf(sD[qs][0][0], sD[qs][0][1]), fmaxf(sD[qs][0][2], sD[qs][0][3]));
      float m11 = fmaxf(fmaxf(sD[qs][1][0], sD[qs][1][1]), fmaxf(sD[qs][1][2], sD[qs][1][3]));
      float m21 = fmaxf(fmaxf(sD[qs][2][0], sD[qs][2][1]), fmaxf(sD[qs][2][2], sD[qs][2][3]));
      float m31 = fmaxf(fmaxf(sD[qs][3][0], sD[qs][3][1]), fmaxf(sD[qs][3][2], sD[qs][3][3]));
      float mx = fmaxf(fmaxf(m01, m11), fmaxf(m21, m31));
      mx = fmaxf(mx, __shfl_xor(mx, 16));
      mx = fmaxf(mx, __shfl_xor(mx, 32));
      const float mnew = fmaxf(mrun[qs], mx);
      al[qs] = __expf(mrun[qs] - mnew);
      mrun[qs] = mnew;
      float rs = 0.f;
      unsigned pk[8];
#pragma unroll
      for (int t = 0; t < 4; ++t) {
        const float e0 = __expf(sD[qs][t][0] - mnew);
        const float e1 = __expf(sD[qs][t][1] - mnew);
        const float e2 = __expf(sD[qs][t][2] - mnew);
        const float e3 = __expf(sD[qs][t][3] - mnew);
        rs += (e0 + e1) + (e2 + e3);
        pk[t * 2]     = packpair(e0, e1);
        pk[t * 2 + 1] = packpair(e2, e3);
      }
      rs += __shfl_xor(rs, 16);
      rs += __shfl_xor(rs, 32);
      lrun[qs] = lrun[qs] * al[qs] + rs;
      // P^T rows [q=qs*16+c][key]: packed b64 writes, swizzled
      char* prow = Pls + (qs * 16 + c) * 128;
#pragma unroll
      for (int t = 0; t < 4; ++t)
        *(uint2*)(prow + ((t * 32 + (g << 3)) ^ swc)) = make_uint2(pk[t * 2], pk[t * 2 + 1]);
    }

    // rescale O by al (scalar per lane)
#pragma unroll
    for (int qs = 0; qs < 2; ++qs)
#pragma unroll
      for (int dt = 0; dt < 5; ++dt)
#pragma unroll
        for (int r = 0; r < 4; ++r) Of[qs][dt][r] *= al[qs];

    // ---- O^T += V^T · P^T ----
    short8 pb[2][2];
#pragma unroll
    for (int qs = 0; qs < 2; ++qs) {
      const char* prow = Pls + (qs * 16 + c) * 128;
      pb[qs][0] = *(const short8*)(prow + ((g << 4) ^ swc));
      pb[qs][1] = *(const short8*)(prow + ((64 + (g << 4)) ^ swc));
    }
    __builtin_amdgcn_s_setprio(1);
#pragma unroll
    for (int dt = 0; dt < 5; ++dt) {
      const char* vp = Vls + (dt * 16 + c) * 128;
      const short8 va0 = *(const short8*)(vp + ((g << 4) ^ swc));
      const short8 va1 = *(const short8*)(vp + ((64 + (g << 4)) ^ swc));
#pragma unroll
      for (int qs = 0; qs < 2; ++qs) {
        Of[qs][dt] = __builtin_amdgcn_mfma_f32_16x16x32_bf16(va0, pb[qs][0], Of[qs][dt], 0, 0, 0);
        Of[qs][dt] = __builtin_amdgcn_mfma_f32_16x16x32_bf16(va1, pb[qs][1], Of[qs][dt], 0, 0, 0);
      }
    }
    __builtin_amdgcn_s_setprio(0);

    __syncthreads();
    if (hav) {
      *(uint4*)(Kls + r0 * 128 + so) = ka;
      *(uint4*)(Kls + (r0 + 32) * 128 + so) = kb2;
      *(uint4*)(Vls + r0 * 128 + so) = va;
      *(uint4*)(Vls + (r0 + 32) * 128 + so) = vb2;
      if (tid < 128) *(uint4*)(Vls + (r0 + 64) * 128 + so) = vc;
    }
    __syncthreads();
  }

  // ---- epilogue: direct stores of unnormalized O + (m,l) ----
  const int rowbase = (sp * 4 + h) * 69;
#pragma unroll
  for (int qs = 0; qs < 2; ++qs) {
    const int qg = qbase + w * 32 + qs * 16 + c;
#pragma unroll
    for (int dt = 0; dt < 5; ++dt)
#pragma unroll
      for (int r = 0; r < 4; ++r) {
        const int dv = dt * 16 + (g << 2) + r;
        if (dv < 67) Opart[(size_t)(rowbase + dv) * NN + qg] = Of[qs][dt][r];
      }
    if (g == 0) {
      Opart[(size_t)(rowbase + 67) * NN + qg] = mrun[qs];
      Opart[(size_t)(rowbase + 68) * NN + qg] = lrun[qs];
    }
  }
}

// ---------------- combine: merge splits, augment, write y ----------------
// grid (16, 4, 4): x = q-chunk of 256, y = head, z = dv-chunk
__global__ __launch_bounds__(256) void combine_kernel(
    const float* __restrict__ Opart, const float* __restrict__ coords0,
    float* __restrict__ y, int nsplit) {
  const int q = blockIdx.x * 256 + threadIdx.x;
  const int h = blockIdx.y;
  const int z = blockIdx.z;
  float m[8], w[8];
  float M = -1e30f;
  for (int s = 0; s < nsplit; ++s) {
    m[s] = Opart[((s * 4 + h) * 69 + 67) * (size_t)NN + q];
    M = fmaxf(M, m[s]);
  }
  float L = 0.f;
  for (int s = 0; s < nsplit; ++s) {
    w[s] = __expf(m[s] - M);
    L += Opart[((s * 4 + h) * 69 + 68) * (size_t)NN + q] * w[s];
  }
  const float invL = 1.f / L;
  if (z < 3) {
    const int dv0 = z * 17, dv1 = dv0 + 17;
    for (int dv = dv0; dv < dv1; ++dv) {
      float a = 0.f;
      for (int s = 0; s < nsplit; ++s)
        a += Opart[((s * 4 + h) * 69 + dv) * (size_t)NN + q] * w[s];
      y[(dv * 4 + h) * NN + q] = a * invL;
    }
  } else {
    float ssum = 0.f;
    for (int dv = 51; dv < 67; ++dv) {
      float a = 0.f;
      for (int s = 0; s < nsplit; ++s)
        a += Opart[((s * 4 + h) * 69 + dv) * (size_t)NN + q] * w[s];
      a *= invL;
      y[(dv * 4 + h) * NN + q] = a;
      if (dv >= 64) {
        const float aug = a - coords0[(dv - 64) * NN + q];
        y[((dv + 3) * 4 + h) * NN + q] = aug;
        ssum += aug * aug;
      }
    }
    y[(70 * 4 + h) * NN + q] = sqrtf(ssum);
  }
}

// ---------------- final 284x284 projection ----------------
// grid (16, 36), block 256. Per-thread: 8 out-ch x 1 n.
__global__ __launch_bounds__(256) void outproj_kernel(
    const float* __restrict__ y, const float* __restrict__ Wm, const float* __restrict__ bm,
    float* __restrict__ out) {
  __shared__ float Wl[8][284];
  const int co0 = blockIdx.y * 8;
  const int tid = threadIdx.x;
  for (int idx = tid; idx < 8 * 284; idx += 256) {
    const int j = idx / 284, ci = idx - j * 284;
    const int co = co0 + j;
    Wl[j][ci] = (co < 284) ? Wm[co * 284 + ci] : 0.f;
  }
  __syncthreads();
  const int n = blockIdx.x * 256 + tid;
  float acc[8];
#pragma unroll
  for (int j = 0; j < 8; ++j) {
    const int co = co0 + j;
    acc[j] = (co < 284) ? bm[co] : 0.f;
  }
  for (int c4 = 0; c4 < 284; c4 += 4) {
    const float x0 = y[(c4 + 0) * NN + n];
    const float x1 = y[(c4 + 1) * NN + n];
    const float x2 = y[(c4 + 2) * NN + n];
    const float x3 = y[(c4 + 3) * NN + n];
#pragma unroll
    for (int j = 0; j < 8; ++j) {
      const float4 wv = *(const float4*)&Wl[j][c4];
      acc[j] = fmaf(wv.x, x0, fmaf(wv.y, x1, fmaf(wv.z, x2, fmaf(wv.w, x3, acc[j]))));
    }
  }
#pragma unroll
  for (int j = 0; j < 8; ++j) {
    const int co = co0 + j;
    if (co < 284) out[co * NN + n] = acc[j];
  }
}

extern "C" void kernel_launch(void* const* d_in, const int* in_sizes, int n_in,
                              void* d_out, int out_size, void* d_ws, size_t ws_size,
                              hipStream_t stream) {
  const float* query   = (const float*)d_in[0];
  const float* key_    = (const float*)d_in[1];
  const float* value   = (const float*)d_in[2];
  const float* coords0 = (const float*)d_in[3];
  const float* coords1 = (const float*)d_in[4];
  const float* Wq = (const float*)d_in[5];
  const float* bq = (const float*)d_in[6];
  const float* Wk = (const float*)d_in[7];
  const float* bk = (const float*)d_in[8];
  const float* Wv = (const float*)d_in[9];
  const float* bv = (const float*)d_in[10];
  const float* Wm = (const float*)d_in[11];
  const float* bm = (const float*)d_in[12];
  float* out = (float*)d_out;

  // ws layout: Qb 2MB | Kb 2MB | Vb 2.62MB | y 4.65MB | Opart nsplit*4.52MB
  const size_t base = (size_t)4 * NN * 64 * 2 * 2 + (size_t)4 * 80 * NN * 2 + (size_t)284 * NN * 4;
  const size_t per  = (size_t)4 * 69 * NN * 4;
  int nsplit = 8;
  while (nsplit > 1 && ws_size < base + (size_t)nsplit * per) nsplit >>= 1;

  unsigned short* Qb = (unsigned short*)d_ws;
  unsigned short* Kb = Qb + 4 * NN * 64;
  unsigned short* Vb = Kb + 4 * NN * 64;
  float* y = (float*)(Vb + 4 * 80 * NN);
  float* Opart = y + (size_t)284 * NN;

  hipLaunchKernelGGL(proj_kernel, dim3(16, 16, 3), dim3(256), 0, stream,
                     query, key_, value, Wq, bq, Wk, bk, Wv, bv, Qb, Kb, Vb);
  hipLaunchKernelGGL(coords_fill_kernel, dim3(16, 4), dim3(256), 0, stream, coords1, Vb);
  hipLaunchKernelGGL(attn_kernel, dim3(32, 4, nsplit), dim3(256), 0, stream,
                     Qb, Kb, Vb, Opart, NN / nsplit);
  hipLaunchKernelGGL(combine_kernel, dim3(16, 4, 4), dim3(256), 0, stream,
                     Opart, coords0, y, nsplit);
  hipLaunchKernelGGL(outproj_kernel, dim3(16, 36), dim3(256), 0, stream, y, Wm, bm, out);
}

// Round 4
// 136.473 us; speedup vs baseline: 2.0918x; 1.2938x over previous
//
#include <hip/hip_runtime.h>
#include <hip/hip_bf16.h>

#define NN 4096

typedef __attribute__((ext_vector_type(8))) short short8;
typedef __attribute__((ext_vector_type(4))) float f32x4;

__device__ __forceinline__ unsigned short f2bf(float f) {
  union { float f; unsigned u; } v; v.f = f;
  unsigned u = v.u;
  u += 0x7fffu + ((u >> 16) & 1u);
  return (unsigned short)(u >> 16);
}

__device__ __forceinline__ unsigned packpair(float a, float b) {
  __hip_bfloat162 h = __float22bfloat162_rn(make_float2(a, b));  // v_cvt_pk_bf16_f32
  union { __hip_bfloat162 h; unsigned u; } cv; cv.h = h;
  return cv.u;
}

// ---------------- transpose q/k/v: f32 [256][NN] -> bf16 [NN][256] ----------------
// grid (64, 4, 3), block 256
__global__ __launch_bounds__(256) void transpose3_kernel(
    const float* __restrict__ q, const float* __restrict__ k, const float* __restrict__ v,
    unsigned short* __restrict__ Xt) {
  __shared__ float Tl[64][65];
  const float* X = (blockIdx.z == 0) ? q : (blockIdx.z == 1) ? k : v;
  unsigned short* dst = Xt + (size_t)blockIdx.z * NN * 256;
  const int n0 = blockIdx.x << 6, k0 = blockIdx.y << 6;
  const int t = threadIdx.x;
  const int r = t >> 4, c4 = (t & 15) << 2;
#pragma unroll
  for (int i = 0; i < 4; ++i) {
    const float4 vv = *(const float4*)(X + (size_t)(k0 + r + 16 * i) * NN + n0 + c4);
    Tl[r + 16 * i][c4] = vv.x; Tl[r + 16 * i][c4 + 1] = vv.y;
    Tl[r + 16 * i][c4 + 2] = vv.z; Tl[r + 16 * i][c4 + 3] = vv.w;
  }
  __syncthreads();
  const int kc = (t & 7) << 3;
#pragma unroll
  for (int j = 0; j < 2; ++j) {
    const int n = (t >> 3) + (j << 5);
    unsigned pk[4];
#pragma unroll
    for (int u = 0; u < 4; ++u)
      pk[u] = packpair(Tl[kc + 2 * u][n], Tl[kc + 2 * u + 1][n]);
    *(uint4*)(dst + (size_t)(n0 + n) * 256 + k0 + kc) = *(uint4*)pk;
  }
}

// ---------------- transpose with pad: f32 [R][NN] -> bf16 [NN][Rpad], zero pad ----------------
// grid (64, ceil(Rpad/64)), block 256
__global__ __launch_bounds__(256) void transpose_pad_kernel(
    const float* __restrict__ X, unsigned short* __restrict__ dst, int R, int Rpad) {
  __shared__ float Tl[64][65];
  const int n0 = blockIdx.x << 6, k0 = blockIdx.y << 6;
  const int t = threadIdx.x;
  const int r = t >> 4, c4 = (t & 15) << 2;
#pragma unroll
  for (int i = 0; i < 4; ++i) {
    const int kk = k0 + r + 16 * i;
    float4 vv = make_float4(0.f, 0.f, 0.f, 0.f);
    if (kk < R) vv = *(const float4*)(X + (size_t)kk * NN + n0 + c4);
    Tl[r + 16 * i][c4] = vv.x; Tl[r + 16 * i][c4 + 1] = vv.y;
    Tl[r + 16 * i][c4 + 2] = vv.z; Tl[r + 16 * i][c4 + 3] = vv.w;
  }
  __syncthreads();
  const int kc = (t & 7) << 3;
  if (k0 + kc < Rpad) {
#pragma unroll
    for (int j = 0; j < 2; ++j) {
      const int n = (t >> 3) + (j << 5);
      unsigned pk[4];
#pragma unroll
      for (int u = 0; u < 4; ++u)
        pk[u] = packpair(Tl[kc + 2 * u][n], Tl[kc + 2 * u + 1][n]);
      *(uint4*)(dst + (size_t)(n0 + n) * Rpad + k0 + kc) = *(uint4*)pk;
    }
  }
}

// ---------------- MFMA projection GEMM: C = W(256x256) . X(256xNN) ----------------
// grid (NN/128, 4, 3), block 256 = 4 waves (2x2). BM=64, BN=128, BK=64.
// Epilogue: z=0 -> Qb [h][n][64] scaled 0.125; z=1 -> Kb; z=2 -> Vb [h*80+d][n].
#define PROJ_LOAD(k0_) do { \
  _Pragma("unroll") for (int i = 0; i < 4; ++i) \
    wa[i] = *(const float4*)(W + (size_t)(co0 + ar) * 256 + (k0_) + ac + 4 * i); \
  _Pragma("unroll") for (int i = 0; i < 4; ++i) \
    wb[i] = *(const uint4*)(Xz + (size_t)(n0 + bn + (i << 5)) * 256 + (k0_) + bc); \
} while (0)

#define PROJ_WRITE_LDS() do { \
  unsigned pk[8]; \
  _Pragma("unroll") for (int i = 0; i < 4; ++i) { \
    pk[2 * i] = packpair(wa[i].x, wa[i].y); \
    pk[2 * i + 1] = packpair(wa[i].z, wa[i].w); \
  } \
  *(uint4*)(Al + ar * 128 + (((ac << 1)) ^ aswz)) = *(uint4*)&pk[0]; \
  *(uint4*)(Al + ar * 128 + (((ac << 1) + 16) ^ aswz)) = *(uint4*)&pk[4]; \
  _Pragma("unroll") for (int i = 0; i < 4; ++i) \
    *(uint4*)(Bl + (bn + (i << 5)) * 128 + (((bc << 1)) ^ bswz)) = wb[i]; \
} while (0)

__global__ __launch_bounds__(256) void proj_gemm_kernel(
    const float* __restrict__ Wq, const float* __restrict__ bq,
    const float* __restrict__ Wk, const float* __restrict__ bk,
    const float* __restrict__ Wv, const float* __restrict__ bv,
    const unsigned short* __restrict__ Xt,
    unsigned short* __restrict__ Qb, unsigned short* __restrict__ Kb,
    unsigned short* __restrict__ Vb) {
  __shared__ __align__(16) unsigned char smem[24576];  // Al 64x128B | Bl 128x128B
  __shared__ float Bls[64];
  const int z = blockIdx.z;
  const float* W  = (z == 0) ? Wq : (z == 1) ? Wk : Wv;
  const float* bb = (z == 0) ? bq : (z == 1) ? bk : bv;
  const unsigned short* Xz = Xt + (size_t)z * NN * 256;
  const int co0 = blockIdx.y << 6;
  const int n0 = blockIdx.x << 7;
  const int tid = threadIdx.x;
  const int w = tid >> 6, l = tid & 63;
  const int wm = w >> 1, wn = w & 1;
  const int c = l & 15, g = l >> 4;
  char* const Al = (char*)smem;
  char* const Bl = (char*)smem + 8192;

  if (tid < 64) Bls[tid] = bb[co0 + tid];

  const int ar = tid >> 2, ac = (tid & 3) << 4;
  const int bn = tid >> 3, bc = (tid & 7) << 3;
  const int aswz = (ar & 7) << 4;
  const int bswz = (bn & 7) << 4;

  float4 wa[4];
  uint4 wb[4];
  f32x4 acc[2][4];
#pragma unroll
  for (int mf = 0; mf < 2; ++mf)
#pragma unroll
    for (int nf = 0; nf < 4; ++nf) acc[mf][nf] = (f32x4){0.f, 0.f, 0.f, 0.f};

  PROJ_LOAD(0);
  PROJ_WRITE_LDS();
  __syncthreads();

  for (int s = 0; s < 4; ++s) {
    const bool hav = (s + 1 < 4);
    if (hav) PROJ_LOAD((s + 1) << 6);
    __builtin_amdgcn_s_setprio(1);
#pragma unroll
    for (int ks = 0; ks < 2; ++ks) {
      short8 af[2], bf[4];
#pragma unroll
      for (int mf = 0; mf < 2; ++mf) {
        const int row = wm * 32 + mf * 16 + c;
        af[mf] = *(const short8*)(Al + row * 128 + (((ks << 6) + (g << 4)) ^ ((row & 7) << 4)));
      }
#pragma unroll
      for (int nf = 0; nf < 4; ++nf) {
        const int row = wn * 64 + nf * 16 + c;
        bf[nf] = *(const short8*)(Bl + row * 128 + (((ks << 6) + (g << 4)) ^ ((row & 7) << 4)));
      }
#pragma unroll
      for (int mf = 0; mf < 2; ++mf)
#pragma unroll
        for (int nf = 0; nf < 4; ++nf)
          acc[mf][nf] = __builtin_amdgcn_mfma_f32_16x16x32_bf16(af[mf], bf[nf], acc[mf][nf], 0, 0, 0);
    }
    __builtin_amdgcn_s_setprio(0);
    __syncthreads();
    if (hav) PROJ_WRITE_LDS();
    __syncthreads();
  }

  // epilogue: acc -> LDS bounce (bf16, stride 136) -> layout-specific global writes
  unsigned short* Clu = (unsigned short*)smem;  // [64][136]
  const float scale = (z == 0) ? 0.125f : 1.0f;
#pragma unroll
  for (int mf = 0; mf < 2; ++mf)
#pragma unroll
    for (int nf = 0; nf < 4; ++nf)
#pragma unroll
      for (int rr = 0; rr < 4; ++rr) {
        const int row = wm * 32 + mf * 16 + (g << 2) + rr;
        const int col = wn * 64 + nf * 16 + c;
        Clu[row * 136 + col] = f2bf((acc[mf][nf][rr] + Bls[row]) * scale);
      }
  __syncthreads();
  if (z <= 1) {
    unsigned short* Ob = (z == 0) ? Qb : Kb;
    const int d0 = co0 >> 2;
#pragma unroll
    for (int j = 0; j < 2; ++j) {
      const int pair = tid + (j << 8);
      const int h = pair >> 7, n = pair & 127;
      unsigned u[8];
#pragma unroll
      for (int p = 0; p < 8; ++p)
        u[p] = (unsigned)Clu[((p << 3) + h) * 136 + n] |
               ((unsigned)Clu[((p << 3) + 4 + h) * 136 + n] << 16);
      uint4* dst = (uint4*)(Ob + ((size_t)h * NN + n0 + n) * 64 + d0);
      dst[0] = *(uint4*)&u[0];
      dst[1] = *(uint4*)&u[4];
    }
  } else {
    const int rl = tid >> 2, ch4 = (tid & 3) << 5;
    const int h = rl & 3, d = (co0 >> 2) + (rl >> 2);
    unsigned short* vd = Vb + (size_t)(h * 80 + d) * NN + n0 + ch4;
#pragma unroll
    for (int i = 0; i < 4; ++i)
      *(uint4*)(vd + (i << 3)) = *(const uint4*)((char*)Clu + rl * 272 + (ch4 << 1) + (i << 4));
  }
}

// ---------------- coords fill: V rows 64..66 = coords1, 67..79 = 0 ----------------
__global__ void coords_fill_kernel(const float* __restrict__ coords1, unsigned short* __restrict__ Vb) {
  const int n = blockIdx.x * 256 + threadIdx.x;
  const int h = blockIdx.y;
#pragma unroll
  for (int i = 0; i < 3; ++i)
    Vb[(h * 80 + 64 + i) * NN + n] = f2bf(coords1[i * NN + n]);
#pragma unroll
  for (int d = 67; d < 80; ++d)
    Vb[(h * 80 + d) * NN + n] = 0;
}

// ---------------- fused flash attention (split-K, swapped-S^T, async stage) ----------------
// grid (32, 4, nsplit): x = q-tile of 128, y = head, z = key-split.
__global__ __launch_bounds__(256) void attn_kernel(
    const unsigned short* __restrict__ Qb, const unsigned short* __restrict__ Kb,
    const unsigned short* __restrict__ Vb, float* __restrict__ Opart, int chunkKeys) {
  __shared__ __align__(16) unsigned char smem[34816];  // K 8192 | Vt 10240 | P 4x4096
  const int h = blockIdx.y;
  const int sp = blockIdx.z;
  const int qbase = blockIdx.x * 128;
  const int tid = threadIdx.x;
  const int w = tid >> 6;
  const int l = tid & 63;
  const int c = l & 15;
  const int g = l >> 4;
  const int swc = (c & 7) << 4;

  char* const Kls = (char*)smem;
  char* const Vls = (char*)smem + 8192;
  char* const Pls = (char*)smem + 18432 + w * 4096;

  short8 qf[2][2];
#pragma unroll
  for (int qs = 0; qs < 2; ++qs) {
    const unsigned short* qsrc = Qb + (((h * NN) + qbase + w * 32 + qs * 16 + c) << 6) + (g << 3);
    qf[qs][0] = *(const short8*)qsrc;
    qf[qs][1] = *(const short8*)(qsrc + 32);
  }

  f32x4 Of[2][5];
#pragma unroll
  for (int qs = 0; qs < 2; ++qs)
#pragma unroll
    for (int dt = 0; dt < 5; ++dt) Of[qs][dt] = (f32x4){0.f, 0.f, 0.f, 0.f};
  float mrun[2] = {-1e30f, -1e30f};
  float lrun[2] = {0.f, 0.f};

  const int r0 = tid >> 3, ch = tid & 7;
  const int so = (ch << 4) ^ ((r0 & 7) << 4);
  const int mStart = sp * chunkKeys;
  const int niter = chunkKeys >> 6;

  {
    const unsigned short* kbase = Kb + ((h * NN + mStart) << 6);
    const unsigned short* vbase = Vb + (size_t)(h * 80) * NN + mStart;
    const uint4 ka  = *(const uint4*)(kbase + (r0 << 6) + (ch << 3));
    const uint4 kb2 = *(const uint4*)(kbase + ((r0 + 32) << 6) + (ch << 3));
    const uint4 va  = *(const uint4*)(vbase + (size_t)r0 * NN + (ch << 3));
    const uint4 vb2 = *(const uint4*)(vbase + (size_t)(r0 + 32) * NN + (ch << 3));
    *(uint4*)(Kls + r0 * 128 + so) = ka;
    *(uint4*)(Kls + (r0 + 32) * 128 + so) = kb2;
    *(uint4*)(Vls + r0 * 128 + so) = va;
    *(uint4*)(Vls + (r0 + 32) * 128 + so) = vb2;
    if (tid < 128) {
      const uint4 vc = *(const uint4*)(vbase + (size_t)(r0 + 64) * NN + (ch << 3));
      *(uint4*)(Vls + (r0 + 64) * 128 + so) = vc;
    }
  }
  __syncthreads();

  for (int it = 0; it < niter; ++it) {
    uint4 ka, kb2, va, vb2, vc;
    const bool hav = (it + 1 < niter);
    if (hav) {
      const int m0 = mStart + ((it + 1) << 6);
      const unsigned short* kbase = Kb + ((h * NN + m0) << 6);
      const unsigned short* vbase = Vb + (size_t)(h * 80) * NN + m0;
      ka  = *(const uint4*)(kbase + (r0 << 6) + (ch << 3));
      kb2 = *(const uint4*)(kbase + ((r0 + 32) << 6) + (ch << 3));
      va  = *(const uint4*)(vbase + (size_t)r0 * NN + (ch << 3));
      vb2 = *(const uint4*)(vbase + (size_t)(r0 + 32) * NN + (ch << 3));
      if (tid < 128) vc = *(const uint4*)(vbase + (size_t)(r0 + 64) * NN + (ch << 3));
    }

    f32x4 sD[2][4];
    __builtin_amdgcn_s_setprio(1);
#pragma unroll
    for (int t = 0; t < 4; ++t) {
      const char* rp = Kls + (t * 16 + c) * 128;
      const short8 ka0 = *(const short8*)(rp + ((g << 4) ^ swc));
      const short8 ka1 = *(const short8*)(rp + ((64 + (g << 4)) ^ swc));
#pragma unroll
      for (int qs = 0; qs < 2; ++qs) {
        f32x4 a = (f32x4){0.f, 0.f, 0.f, 0.f};
        a = __builtin_amdgcn_mfma_f32_16x16x32_bf16(ka0, qf[qs][0], a, 0, 0, 0);
        a = __builtin_amdgcn_mfma_f32_16x16x32_bf16(ka1, qf[qs][1], a, 0, 0, 0);
        sD[qs][t] = a;
      }
    }
    __builtin_amdgcn_s_setprio(0);

    float al[2];
#pragma unroll
    for (int qs = 0; qs < 2; ++qs) {
      float m01 = fmaxf(fmaxf(sD[qs][0][0], sD[qs][0][1]), fmaxf(sD[qs][0][2], sD[qs][0][3]));
      float m11 = fmaxf(fmaxf(sD[qs][1][0], sD[qs][1][1]), fmaxf(sD[qs][1][2], sD[qs][1][3]));
      float m21 = fmaxf(fmaxf(sD[qs][2][0], sD[qs][2][1]), fmaxf(sD[qs][2][2], sD[qs][2][3]));
      float m31 = fmaxf(fmaxf(sD[qs][3][0], sD[qs][3][1]), fmaxf(sD[qs][3][2], sD[qs][3][3]));
      float mx = fmaxf(fmaxf(m01, m11), fmaxf(m21, m31));
      mx = fmaxf(mx, __shfl_xor(mx, 16));
      mx = fmaxf(mx, __shfl_xor(mx, 32));
      const float mnew = fmaxf(mrun[qs], mx);
      al[qs] = __expf(mrun[qs] - mnew);
      mrun[qs] = mnew;
      float rs = 0.f;
      unsigned pk[8];
#pragma unroll
      for (int t = 0; t < 4; ++t) {
        const float e0 = __expf(sD[qs][t][0] - mnew);
        const float e1 = __expf(sD[qs][t][1] - mnew);
        const float e2 = __expf(sD[qs][t][2] - mnew);
        const float e3 = __expf(sD[qs][t][3] - mnew);
        rs += (e0 + e1) + (e2 + e3);
        pk[t * 2]     = packpair(e0, e1);
        pk[t * 2 + 1] = packpair(e2, e3);
      }
      rs += __shfl_xor(rs, 16);
      rs += __shfl_xor(rs, 32);
      lrun[qs] = lrun[qs] * al[qs] + rs;
      char* prow = Pls + (qs * 16 + c) * 128;
#pragma unroll
      for (int t = 0; t < 4; ++t)
        *(uint2*)(prow + ((t * 32 + (g << 3)) ^ swc)) = make_uint2(pk[t * 2], pk[t * 2 + 1]);
    }

#pragma unroll
    for (int qs = 0; qs < 2; ++qs)
#pragma unroll
      for (int dt = 0; dt < 5; ++dt)
#pragma unroll
        for (int r = 0; r < 4; ++r) Of[qs][dt][r] *= al[qs];

    short8 pb[2][2];
#pragma unroll
    for (int qs = 0; qs < 2; ++qs) {
      const char* prow = Pls + (qs * 16 + c) * 128;
      pb[qs][0] = *(const short8*)(prow + ((g << 4) ^ swc));
      pb[qs][1] = *(const short8*)(prow + ((64 + (g << 4)) ^ swc));
    }
    __builtin_amdgcn_s_setprio(1);
#pragma unroll
    for (int dt = 0; dt < 5; ++dt) {
      const char* vp = Vls + (dt * 16 + c) * 128;
      const short8 va0 = *(const short8*)(vp + ((g << 4) ^ swc));
      const short8 va1 = *(const short8*)(vp + ((64 + (g << 4)) ^ swc));
#pragma unroll
      for (int qs = 0; qs < 2; ++qs) {
        Of[qs][dt] = __builtin_amdgcn_mfma_f32_16x16x32_bf16(va0, pb[qs][0], Of[qs][dt], 0, 0, 0);
        Of[qs][dt] = __builtin_amdgcn_mfma_f32_16x16x32_bf16(va1, pb[qs][1], Of[qs][dt], 0, 0, 0);
      }
    }
    __builtin_amdgcn_s_setprio(0);

    __syncthreads();
    if (hav) {
      *(uint4*)(Kls + r0 * 128 + so) = ka;
      *(uint4*)(Kls + (r0 + 32) * 128 + so) = kb2;
      *(uint4*)(Vls + r0 * 128 + so) = va;
      *(uint4*)(Vls + (r0 + 32) * 128 + so) = vb2;
      if (tid < 128) *(uint4*)(Vls + (r0 + 64) * 128 + so) = vc;
    }
    __syncthreads();
  }

  const int rowbase = (sp * 4 + h) * 69;
#pragma unroll
  for (int qs = 0; qs < 2; ++qs) {
    const int qg = qbase + w * 32 + qs * 16 + c;
#pragma unroll
    for (int dt = 0; dt < 5; ++dt)
#pragma unroll
      for (int r = 0; r < 4; ++r) {
        const int dv = dt * 16 + (g << 2) + r;
        if (dv < 67) Opart[(size_t)(rowbase + dv) * NN + qg] = Of[qs][dt][r];
      }
    if (g == 0) {
      Opart[(size_t)(rowbase + 67) * NN + qg] = mrun[qs];
      Opart[(size_t)(rowbase + 68) * NN + qg] = lrun[qs];
    }
  }
}

// ---------------- combine: merge splits, augment, write y f32 [284][NN] ----------------
// grid (16, 4, 4)
__global__ __launch_bounds__(256) void combine_kernel(
    const float* __restrict__ Opart, const float* __restrict__ coords0,
    float* __restrict__ y, int nsplit) {
  const int q = blockIdx.x * 256 + threadIdx.x;
  const int h = blockIdx.y;
  const int z = blockIdx.z;
  float m[8], w[8];
  float M = -1e30f;
  for (int s = 0; s < nsplit; ++s) {
    m[s] = Opart[((s * 4 + h) * 69 + 67) * (size_t)NN + q];
    M = fmaxf(M, m[s]);
  }
  float L = 0.f;
  for (int s = 0; s < nsplit; ++s) {
    w[s] = __expf(m[s] - M);
    L += Opart[((s * 4 + h) * 69 + 68) * (size_t)NN + q] * w[s];
  }
  const float invL = 1.f / L;
  if (z < 3) {
    const int dv0 = z * 17, dv1 = dv0 + 17;
    for (int dv = dv0; dv < dv1; ++dv) {
      float a = 0.f;
      for (int s = 0; s < nsplit; ++s)
        a += Opart[((s * 4 + h) * 69 + dv) * (size_t)NN + q] * w[s];
      y[(dv * 4 + h) * NN + q] = a * invL;
    }
  } else {
    float ssum = 0.f;
    for (int dv = 51; dv < 67; ++dv) {
      float a = 0.f;
      for (int s = 0; s < nsplit; ++s)
        a += Opart[((s * 4 + h) * 69 + dv) * (size_t)NN + q] * w[s];
      a *= invL;
      y[(dv * 4 + h) * NN + q] = a;
      if (dv >= 64) {
        const float aug = a - coords0[(dv - 64) * NN + q];
        y[((dv + 3) * 4 + h) * NN + q] = aug;
        ssum += aug * aug;
      }
    }
    y[(70 * 4 + h) * NN + q] = sqrtf(ssum);
  }
}

// ---------------- MFMA out projection: out = Wm(284x284) . y + bm ----------------
// grid (NN/128, 5), block 256 = 4 waves (2x2). BM=64, BN=128, BK=96, K=288.
// LDS rows padded to 256B so XOR swizzle stays in-row.
#define OP_LOAD(k0_) do { \
  const int arow = co0 + ar; \
  _Pragma("unroll") for (int i = 0; i < 6; ++i) { \
    const int col = (k0_) + ac + 4 * i; \
    wa[i] = (arow < 284 && col < 284) ? *(const float4*)(Wm + (size_t)arow * 284 + col) \
                                      : make_float4(0.f, 0.f, 0.f, 0.f); \
  } \
  _Pragma("unroll") for (int i = 0; i < 6; ++i) \
    wb[i] = *(const uint4*)(Yt + (size_t)(n0 + bn) * 288 + (k0_) + bc + 8 * i); \
} while (0)

#define OP_WRITE_LDS() do { \
  unsigned pk[12]; \
  _Pragma("unroll") for (int i = 0; i < 6; ++i) { \
    pk[2 * i] = packpair(wa[i].x, wa[i].y); \
    pk[2 * i + 1] = packpair(wa[i].z, wa[i].w); \
  } \
  _Pragma("unroll") for (int i = 0; i < 3; ++i) \
    *(uint4*)(Al + ar * 256 + (((ac << 1) + (i << 4)) ^ aswz)) = *(uint4*)&pk[4 * i]; \
  _Pragma("unroll") for (int i = 0; i < 6; ++i) \
    *(uint4*)(Bl + bn * 256 + (((bc << 1) + (i << 4)) ^ bswz)) = wb[i]; \
} while (0)

__global__ __launch_bounds__(256) void outproj_gemm_kernel(
    const unsigned short* __restrict__ Yt, const float* __restrict__ Wm,
    const float* __restrict__ bm, float* __restrict__ out) {
  __shared__ __align__(16) unsigned char smem[49152];  // Al 64x256B | Bl 128x256B
  __shared__ float Bls[64];
  const int co0 = blockIdx.y << 6;
  const int n0 = blockIdx.x << 7;
  const int tid = threadIdx.x;
  const int w = tid >> 6, l = tid & 63;
  const int wm = w >> 1, wn = w & 1;
  const int c = l & 15, g = l >> 4;
  char* const Al = (char*)smem;
  char* const Bl = (char*)smem + 16384;

  if (tid < 64) { const int co = co0 + tid; Bls[tid] = (co < 284) ? bm[co] : 0.f; }

  const int ar = tid >> 2, ac = (tid & 3) * 24;   // A: 64 rows x 96 cols f32
  const int bn = tid >> 1, bc = (tid & 1) * 48;   // B: 128 rows x 96 cols bf16
  const int aswz = (ar & 7) << 4;
  const int bswz = (bn & 7) << 4;

  float4 wa[6];
  uint4 wb[6];
  f32x4 acc[2][4];
#pragma unroll
  for (int mf = 0; mf < 2; ++mf)
#pragma unroll
    for (int nf = 0; nf < 4; ++nf) acc[mf][nf] = (f32x4){0.f, 0.f, 0.f, 0.f};

  OP_LOAD(0);
  OP_WRITE_LDS();
  __syncthreads();

  for (int s = 0; s < 3; ++s) {
    const bool hav = (s + 1 < 3);
    if (hav) OP_LOAD((s + 1) * 96);
    __builtin_amdgcn_s_setprio(1);
#pragma unroll
    for (int ks = 0; ks < 3; ++ks) {
      short8 af[2], bf[4];
#pragma unroll
      for (int mf = 0; mf < 2; ++mf) {
        const int row = wm * 32 + mf * 16 + c;
        af[mf] = *(const short8*)(Al + row * 256 + (((ks << 6) + (g << 4)) ^ ((row & 7) << 4)));
      }
#pragma unroll
      for (int nf = 0; nf < 4; ++nf) {
        const int row = wn * 64 + nf * 16 + c;
        bf[nf] = *(const short8*)(Bl + row * 256 + (((ks << 6) + (g << 4)) ^ ((row & 7) << 4)));
      }
#pragma unroll
      for (int mf = 0; mf < 2; ++mf)
#pragma unroll
        for (int nf = 0; nf < 4; ++nf)
          acc[mf][nf] = __builtin_amdgcn_mfma_f32_16x16x32_bf16(af[mf], bf[nf], acc[mf][nf], 0, 0, 0);
    }
    __builtin_amdgcn_s_setprio(0);
    __syncthreads();
    if (hav) OP_WRITE_LDS();
    __syncthreads();
  }

#pragma unroll
  for (int mf = 0; mf < 2; ++mf)
#pragma unroll
    for (int nf = 0; nf < 4; ++nf)
#pragma unroll
      for (int rr = 0; rr < 4; ++rr) {
        const int row = wm * 32 + mf * 16 + (g << 2) + rr;
        const int co = co0 + row;
        if (co < 284)
          out[(size_t)co * NN + n0 + wn * 64 + nf * 16 + c] = acc[mf][nf][rr] + Bls[row];
      }
}

extern "C" void kernel_launch(void* const* d_in, const int* in_sizes, int n_in,
                              void* d_out, int out_size, void* d_ws, size_t ws_size,
                              hipStream_t stream) {
  const float* query   = (const float*)d_in[0];
  const float* key_    = (const float*)d_in[1];
  const float* value   = (const float*)d_in[2];
  const float* coords0 = (const float*)d_in[3];
  const float* coords1 = (const float*)d_in[4];
  const float* Wq = (const float*)d_in[5];
  const float* bq = (const float*)d_in[6];
  const float* Wk = (const float*)d_in[7];
  const float* bk = (const float*)d_in[8];
  const float* Wv = (const float*)d_in[9];
  const float* bv = (const float*)d_in[10];
  const float* Wm = (const float*)d_in[11];
  const float* bm = (const float*)d_in[12];
  float* out = (float*)d_out;

  // ws: Qb 2MB | Kb 2MB | Vb 2.62MB | Xt 6MB | Yt 2.25MB | y 4.65MB | Opart nsplit*4.52MB
  unsigned short* Qb = (unsigned short*)d_ws;
  unsigned short* Kb = Qb + (size_t)4 * NN * 64;
  unsigned short* Vb = Kb + (size_t)4 * NN * 64;
  unsigned short* Xt = Vb + (size_t)4 * 80 * NN;
  unsigned short* Yt = Xt + (size_t)3 * NN * 256;
  float* y = (float*)(Yt + (size_t)NN * 288);
  float* Opart = y + (size_t)284 * NN;

  const size_t fixedB = (size_t)((char*)Opart - (char*)d_ws);
  const size_t per = (size_t)4 * 69 * NN * 4;
  int nsplit = 8;
  while (nsplit > 1 && ws_size < fixedB + (size_t)nsplit * per) nsplit >>= 1;

  hipLaunchKernelGGL(transpose3_kernel, dim3(64, 4, 3), dim3(256), 0, stream,
                     query, key_, value, Xt);
  hipLaunchKernelGGL(proj_gemm_kernel, dim3(32, 4, 3), dim3(256), 0, stream,
                     Wq, bq, Wk, bk, Wv, bv, Xt, Qb, Kb, Vb);
  hipLaunchKernelGGL(coords_fill_kernel, dim3(16, 4), dim3(256), 0, stream, coords1, Vb);
  hipLaunchKernelGGL(attn_kernel, dim3(32, 4, nsplit), dim3(256), 0, stream,
                     Qb, Kb, Vb, Opart, NN / nsplit);
  hipLaunchKernelGGL(combine_kernel, dim3(16, 4, 4), dim3(256), 0, stream,
                     Opart, coords0, y, nsplit);
  hipLaunchKernelGGL(transpose_pad_kernel, dim3(64, 5), dim3(256), 0, stream, y, Yt, 284, 288);
  hipLaunchKernelGGL(outproj_gemm_kernel, dim3(32, 5), dim3(256), 0, stream, Yt, Wm, bm, out);
}